// Round 21
// baseline (120.205 us; speedup 1.0000x reference)
//
#include <hip/hip_runtime.h>

#define Bn 64
#define Tn 512
#define Hn 768
#define Ln 21
#define EM_ELEMS (Bn*Tn*Ln)
#define NCH 16   // chunks per batch (32 real steps each)

// ws float offsets
#define DELTA_OFF 0      // [1024] per (b,c) NLL log-growth
#define LA0_OFF   1024   // [64]  log sum at t=0
#define W_OFF2    1088   // [64]  et-weighted final ratio
#define SCORE_OFF 1152   // [64]  gold score
#define TAG_OFF   1216   // [64]  final viterbi tag (int)

__device__ __forceinline__ float rl(float x, int i){
    return __int_as_float(__builtin_amdgcn_readlane(__float_as_int(x), i));
}

// 21 readlanes into 21 DISTINCT SGPRs in one asm block (pipelined, no SGPR reuse hazard)
// NOTE: loops containing this macro MUST stay rolled — 8x unrolling it miscompiled (r9/r10: inf).
#define READLANES(src, A) \
    asm volatile( \
        "v_readlane_b32 %0, %[v], 0\n\t" \
        "v_readlane_b32 %1, %[v], 1\n\t" \
        "v_readlane_b32 %2, %[v], 2\n\t" \
        "v_readlane_b32 %3, %[v], 3\n\t" \
        "v_readlane_b32 %4, %[v], 4\n\t" \
        "v_readlane_b32 %5, %[v], 5\n\t" \
        "v_readlane_b32 %6, %[v], 6\n\t" \
        "v_readlane_b32 %7, %[v], 7\n\t" \
        "v_readlane_b32 %8, %[v], 8\n\t" \
        "v_readlane_b32 %9, %[v], 9\n\t" \
        "v_readlane_b32 %10, %[v], 10\n\t" \
        "v_readlane_b32 %11, %[v], 11\n\t" \
        "v_readlane_b32 %12, %[v], 12\n\t" \
        "v_readlane_b32 %13, %[v], 13\n\t" \
        "v_readlane_b32 %14, %[v], 14\n\t" \
        "v_readlane_b32 %15, %[v], 15\n\t" \
        "v_readlane_b32 %16, %[v], 16\n\t" \
        "v_readlane_b32 %17, %[v], 17\n\t" \
        "v_readlane_b32 %18, %[v], 18\n\t" \
        "v_readlane_b32 %19, %[v], 19\n\t" \
        "v_readlane_b32 %20, %[v], 20\n\t" \
        : "=s"(A[0]),"=s"(A[1]),"=s"(A[2]),"=s"(A[3]),"=s"(A[4]), \
          "=s"(A[5]),"=s"(A[6]),"=s"(A[7]),"=s"(A[8]),"=s"(A[9]), \
          "=s"(A[10]),"=s"(A[11]),"=s"(A[12]),"=s"(A[13]),"=s"(A[14]), \
          "=s"(A[15]),"=s"(A[16]),"=s"(A[17]),"=s"(A[18]),"=s"(A[19]), \
          "=s"(A[20]) \
        : [v]"v"(src))

// viterbi step body (r7 verbatim)
#define VIT_STEP(WORD, S) \
    float ec = e1; e1 = e2; \
    e2 = epr[0]; epr += Ln; \
    float A[21]; \
    READLANES(sc, A); \
    float v0=A[0]+trc[0],  v1=A[1]+trc[1],  v2=A[2]+trc[2]; \
    float v3=A[3]+trc[3],  v4=A[4]+trc[4],  v5=A[5]+trc[5]; \
    float v6=A[6]+trc[6],  v7=A[7]+trc[7],  v8=A[8]+trc[8]; \
    float v9=A[9]+trc[9],  v10=A[10]+trc[10],v11=A[11]+trc[11]; \
    float v12=A[12]+trc[12],v13=A[13]+trc[13],v14=A[14]+trc[14]; \
    float v15=A[15]+trc[15],v16=A[16]+trc[16],v17=A[17]+trc[17]; \
    float v18=A[18]+trc[18],v19=A[19]+trc[19],v20=A[20]+trc[20]; \
    float a0 = fmaxf(fmaxf(v0,v1),v2); \
    float a1 = fmaxf(fmaxf(v3,v4),v5); \
    float a2 = fmaxf(fmaxf(v6,v7),v8); \
    float a3 = fmaxf(fmaxf(v9,v10),v11); \
    float a4 = fmaxf(fmaxf(v12,v13),v14); \
    float a5 = fmaxf(fmaxf(v15,v16),v17); \
    float a6 = fmaxf(fmaxf(v18,v19),v20); \
    float b0 = fmaxf(fmaxf(a0,a1),a2); \
    float b1 = fmaxf(fmaxf(a3,a4),a5); \
    float best = fmaxf(fmaxf(b0,b1),a6); \
    float scn = best + ec; \
    int mc = (int)((WORD >> (S)) & 1ull); \
    sc = mc ? scn : sc;

// NLL step body (r7 verbatim)
#define NLL_STEP(WORD, S) \
    float ec = e1; e1 = e2; \
    e2 = epr[0]; epr += Ln; \
    float pe = __expf(ec); \
    float A[21]; \
    READLANES(p, A); \
    float s0=0.f,s1=0.f,s2=0.f; \
    _Pragma("unroll") \
    for (int i=0;i<Ln;++i){ \
        if      (i%3==0) s0 = fmaf(A[i], Ec[i], s0); \
        else if (i%3==1) s1 = fmaf(A[i], Ec[i], s1); \
        else             s2 = fmaf(A[i], Ec[i], s2); \
    } \
    float pn = ((s0+s1)+s2) * pe; \
    int lc = (int)((WORD >> (S)) & 1ull); \
    p = lc ? pn : p; \
    if (((S) & 7) == 0){ \
        float p0 = rl(p, 0); \
        int e; frexpf(p0, &e); \
        p = ldexpf(p, -e); \
        M += (float)e * 0.6931471805599453f; \
    }

// ---------------- emissions = hidden @ W + b  (split-K x4; W via uniform-addr LDS broadcast) ----------------
__global__ __launch_bounds__(256) void emis_kernel(
    const float* __restrict__ hidden, const float* __restrict__ W,
    const float* __restrict__ bias, float* __restrict__ em)
{
    __shared__ float Wl[Hn*Ln];            // 64512 B, staged once
    __shared__ float part[4][64][22];      // 22528 B
    const int tid  = threadIdx.x;
    const int lane = tid & 63;
    const int w    = tid >> 6;
    const int row  = blockIdx.x*64 + lane;
    for (int i=tid; i<Hn*Ln; i+=256) Wl[i] = W[i];
    __syncthreads();
    const float4* h4 = (const float4*)(hidden + (size_t)row*Hn) + w*48;
    const float*  Wp = &Wl[w*(192*Ln)];
    float acc[Ln];
    #pragma unroll
    for (int j=0;j<Ln;++j) acc[j]=0.f;
    float4 hcur = h4[0];
    for (int t=0;t<48;++t){
        float4 hn = (t<47) ? h4[t+1] : hcur;
        const float* hv = &hcur.x;
        const float* Wr = Wp + t*84;       // wave-uniform LDS address -> broadcast ds_read
        #pragma unroll
        for (int c=0;c<4;++c){
            float x = hv[c];
            #pragma unroll
            for (int j=0;j<Ln;++j)
                acc[j] = fmaf(x, Wr[c*Ln+j], acc[j]);
        }
        hcur = hn;
    }
    #pragma unroll
    for (int j=0;j<Ln;++j) part[w][lane][j] = acc[j];
    __syncthreads();
    float* ob = em + (size_t)blockIdx.x*64*Ln;
    for (int e=tid; e<64*Ln; e+=256){
        int r = e/Ln, j = e-r*Ln;
        ob[e] = ((part[0][r][j]+part[1][r][j])+(part[2][r][j]+part[3][r][j])) + bias[j];
    }
}

// ---------------- chunk_scan: 2048 blocks x 64; blk<1024 viterbi chunk, else NLL chunk.
//   chunk (b,c): warmup 32 steps from neutral state (converges), then 32 real steps.
__global__ __launch_bounds__(64) void chunk_scan(
    const float* __restrict__ em, const int* __restrict__ labels,
    const int* __restrict__ amask, const float* __restrict__ st,
    const float* __restrict__ et, const float* __restrict__ trans,
    float* __restrict__ ws, float* __restrict__ alf)
{
    __shared__ float em_s[66*Ln];        // staged rows [w0 .. tstart+31] + 2 pad

    const int mode = blockIdx.x >> 10;   // 0 viterbi, 1 nll
    const int idx  = blockIdx.x & 1023;
    const int b    = idx >> 4;
    const int c    = idx & (NCH-1);
    const int lane = threadIdx.x;
    const bool act = (lane < Ln);
    const int  j   = act ? lane : 0;

    const int tstart = c*32;
    const int WARM   = (c==0) ? 0 : 32;
    const int w0     = tstart - WARM;
    const int nrows  = WARM + 32;

    const float* emg = em + (size_t)b*Tn*Ln;
    for (int i=lane; i<nrows*Ln; i+=64) em_s[i] = emg[(size_t)w0*Ln + i];
    for (int i=lane; i<2*Ln; i+=64){
        int jj = (i < Ln) ? i : (i - Ln);
        em_s[nrows*Ln + i] = em_s[(nrows-1)*Ln + jj];
    }
    __syncthreads();

    if (mode == 0){
        const int* mk = amask + b*Tn;
        // global last unmasked index
        int last = -1;
        #pragma unroll
        for (int k=0;k<8;++k){ int mv = mk[k*64+lane]; if (mv) last = k*64+lane; }
        #pragma unroll
        for (int off=32; off>=1; off>>=1){ int o = __shfl_xor(last, off, 64); last = (o>last)?o:last; }
        const bool owner = (last >= tstart) && (last < tstart+32);

        // one ballot covers steps w0..w0+63 (warm bits 1..31, real bits WARM..WARM+31)
        unsigned long long word = __ballot(mk[w0 + lane] != 0);

        float trc[Ln];
        #pragma unroll
        for (int i=0;i<Ln;++i) trc[i] = trans[i*Ln + j];

        float sc;
        if (c==0) sc = act ? (st[j] + em_s[j]) : -1e30f;
        else      sc = act ? 0.f : -1e30f;

        float* alf_b = alf + (size_t)b*Tn*Ln;
        if (c==0 && act) alf_b[j] = sc;      // row 0 = init

        const float* epr = &em_s[Ln + j];
        float e1 = epr[0]; epr += Ln;
        float e2 = epr[0]; epr += Ln;

        if (c > 0){
            for (int s=1; s<32; ++s){        // warmup (no store)
                VIT_STEP(word, s)
            }
        }
        float* sp = alf_b + (size_t)tstart*Ln + j;
        const int s0i = (c==0) ? 1 : 0;
        for (int s=s0i; s<32; ++s){          // real (store)
            VIT_STEP(word, WARM + s)
            if (act) sp[(size_t)s*Ln] = sc;
        }
        if (owner){
            float val = act ? (sc + et[j]) : -1e30f;
            int   tix = act ? j : 1000;
            #pragma unroll
            for (int off=32; off>=1; off>>=1){
                float ov = __shfl_xor(val, off, 64);
                int   oi = __shfl_xor(tix, off, 64);
                if (ov > val || (ov==val && oi<tix)){ val=ov; tix=oi; }
            }
            if (lane==0) ((int*)(ws+TAG_OFF))[b] = tix;
        }
    } else {
        const int* lb = labels + b*Tn;
        int last = -1;
        #pragma unroll
        for (int k=0;k<8;++k){ int mv = (lb[k*64+lane] != -100) ? 1 : 0; if (mv) last = k*64+lane; }
        #pragma unroll
        for (int off=32; off>=1; off>>=1){ int o = __shfl_xor(last, off, 64); last = (o>last)?o:last; }
        const bool owner = (last >= tstart) && (last < tstart+32);

        unsigned long long word = __ballot(lb[w0 + lane] != -100);

        float Ec[Ln];
        #pragma unroll
        for (int i=0;i<Ln;++i) Ec[i] = __expf(trans[i*Ln + j]);

        float p, M = 0.f, La;
        if (c==0){
            p = act ? __expf(st[j] + em_s[j]) : 0.f;
            float sm = p;
            #pragma unroll
            for (int off=32; off>=1; off>>=1) sm += __shfl_xor(sm, off, 64);
            La = __logf(sm);                 // M=0 at init
        } else {
            p = act ? 1.f : 0.f;
            La = 0.f;                        // set after warmup
        }

        const float* epr = &em_s[Ln + j];
        float e1 = epr[0]; epr += Ln;
        float e2 = epr[0]; epr += Ln;

        if (c > 0){
            for (int s=1; s<32; ++s){        // warmup
                NLL_STEP(word, s)
            }
            float sm = act ? p : 0.f;
            #pragma unroll
            for (int off=32; off>=1; off>>=1) sm += __shfl_xor(sm, off, 64);
            La = M + __logf(sm);
        }
        const int s0i = (c==0) ? 1 : 0;
        for (int s=s0i; s<32; ++s){          // real
            NLL_STEP(word, WARM + s)
        }
        float sm = act ? p : 0.f;
        #pragma unroll
        for (int off=32; off>=1; off>>=1) sm += __shfl_xor(sm, off, 64);
        float Lb = M + __logf(sm);
        if (lane==0) (ws+DELTA_OFF)[b*NCH + c] = Lb - La;
        if (c==0 && lane==0) (ws+LA0_OFF)[b] = La;
        if (owner){
            float wsum = act ? (p * __expf(et[j])) : 0.f;
            #pragma unroll
            for (int off=32; off>=1; off>>=1) wsum += __shfl_xor(wsum, off, 64);
            if (lane==0) (ws+W_OFF2)[b] = __logf(wsum) - __logf(sm);
        }
    }
}

// ---------------- post: blocks 0..63 bp-recompute+backtrack+logits; 64..127 gold score ----------------
__global__ __launch_bounds__(512) void post_kernel(
    const float* __restrict__ em, const int* __restrict__ labels,
    const int* __restrict__ amask, const float* __restrict__ st,
    const float* __restrict__ et, const float* __restrict__ trans,
    float* __restrict__ ws, float* __restrict__ logits)
{
    const int b    = blockIdx.x & (Bn-1);
    const int mode = blockIdx.x >> 6;
    const int tid  = threadIdx.x;

    if (mode == 0){
        __shared__ unsigned char hist_s[Tn*Ln];
        __shared__ int lab_s[Tn];
        __shared__ int path_s[Tn];
        __shared__ unsigned char comp_s[64*Ln];
        __shared__ unsigned char ent_s[64];
        lab_s[tid] = amask[b*Tn + tid];
        const int w = tid >> 6, lane = tid & 63;
        const bool act = lane < Ln;
        const int jc = act ? lane : 0;
        float trc[Ln];
        #pragma unroll
        for (int i=0;i<Ln;++i) trc[i] = trans[i*Ln + jc];
        __syncthreads();
        const float* alf = logits + (size_t)b*Tn*Ln;   // alpha lives here (from chunk_scan)
        for (int t = 1+w; t < Tn; t += 8){
            const float* ar = alf + (size_t)(t-1)*Ln;
            float a[Ln];
            #pragma unroll
            for (int i=0;i<Ln;++i) a[i] = ar[i];
            int bp = lane;
            if (lab_s[t]){
                float v[Ln];
                #pragma unroll
                for (int i=0;i<Ln;++i) v[i] = a[i] + trc[i];
                float a0 = fmaxf(fmaxf(v[0],v[1]),v[2]);
                float a1 = fmaxf(fmaxf(v[3],v[4]),v[5]);
                float a2 = fmaxf(fmaxf(v[6],v[7]),v[8]);
                float a3 = fmaxf(fmaxf(v[9],v[10]),v[11]);
                float a4 = fmaxf(fmaxf(v[12],v[13]),v[14]);
                float a5 = fmaxf(fmaxf(v[15],v[16]),v[17]);
                float a6 = fmaxf(fmaxf(v[18],v[19]),v[20]);
                float b0 = fmaxf(fmaxf(a0,a1),a2);
                float b1 = fmaxf(fmaxf(a3,a4),a5);
                float best = fmaxf(fmaxf(b0,b1),a6);
                unsigned bm = 0u;
                #pragma unroll
                for (int i=0;i<Ln;++i) bm |= (v[i]==best) ? (1u<<i) : 0u;
                bp = __ffs(bm) - 1;
            }
            if (act) hist_s[t*Ln + lane] = (unsigned char)bp;
        }
        __syncthreads();
        if (tid < 64){
            unsigned char cur[Ln];
            #pragma unroll
            for (int q=0;q<Ln;++q) cur[q] = (unsigned char)q;
            #pragma unroll
            for (int k=8;k>=1;--k){
                int ta = 8*tid + k;
                if (ta < Tn){
                    const unsigned char* hr = &hist_s[ta*Ln];
                    #pragma unroll
                    for (int q=0;q<Ln;++q) cur[q] = hr[cur[q]];
                }
            }
            #pragma unroll
            for (int q=0;q<Ln;++q) comp_s[tid*Ln+q] = cur[q];
        }
        __syncthreads();
        if (tid==0){
            int cg = ((const int*)(ws+TAG_OFF))[b];
            for (int l=63;l>=0;--l){ ent_s[l]=(unsigned char)cg; cg = comp_s[l*Ln+cg]; }
        }
        __syncthreads();
        if (tid < 64){
            int s = ent_s[tid];
            if (tid==63) path_s[Tn-1] = s;
            #pragma unroll
            for (int k=8;k>=1;--k){
                int ta = 8*tid + k;
                if (ta < Tn){ s = hist_s[ta*Ln+s]; path_s[ta-1] = s; }
            }
        }
        __syncthreads();   // all alpha reads done; overwrite with one-hot
        float* lg = logits + (size_t)b*Tn*Ln;
        for (int id2=tid; id2<Tn*Ln; id2+=512){
            int t = id2/Ln; int jj = id2 - t*Ln;
            lg[id2] = (lab_s[t] && path_s[t]==jj) ? 1.0f : 0.0f;
        }
    } else {
        __shared__ float red_s[8];
        __shared__ int  redc_s[8];
        const int* lb = labels + b*Tn;
        int labt = lb[tid];
        float term = 0.f;
        int c = (tid==0 || labt != -100) ? 1 : 0;
        if (tid>=1 && labt != -100){
            int lp = lb[tid-1]; if (lp<0) lp=0;
            term = trans[lp*Ln+labt] + em[((size_t)b*Tn+tid)*Ln + labt];
        }
        #pragma unroll
        for (int off=32; off>=1; off>>=1){
            term += __shfl_xor(term, off, 64);
            c    += __shfl_xor(c,    off, 64);
        }
        int w = tid>>6;
        if ((tid&63)==0){ red_s[w]=term; redc_s[w]=c; }
        __syncthreads();
        if (tid==0){
            float sum=0.f; int cnt=0;
            #pragma unroll
            for (int q=0;q<8;++q){ sum+=red_s[q]; cnt+=redc_s[q]; }
            int l0 = lb[0]; int tag0 = l0<0?0:l0;
            float score = st[tag0] + em[(size_t)b*Tn*Ln + tag0] + sum;
            int li = cnt-1; int ll = lb[li]; int lt = ll<0?0:ll;
            score += et[lt];
            (ws+SCORE_OFF)[b] = score;
        }
    }
}

// ---------------- finalize: nll = -mean(score - logZ) ----------------
__global__ __launch_bounds__(64) void fin_kernel(const float* __restrict__ ws,
                                                 float* __restrict__ out0)
{
    const int b = threadIdx.x;
    float logZ = (ws+LA0_OFF)[b] + (ws+W_OFF2)[b];
    #pragma unroll
    for (int c=0;c<NCH;++c) logZ += (ws+DELTA_OFF)[b*NCH + c];
    float v = (ws+SCORE_OFF)[b] - logZ;
    #pragma unroll
    for (int off=32; off>=1; off>>=1) v += __shfl_xor(v, off, 64);
    if (b==0) out0[0] = -(v * (1.0f/64.0f));
}

extern "C" void kernel_launch(void* const* d_in, const int* in_sizes, int n_in,
                              void* d_out, int out_size, void* d_ws, size_t ws_size,
                              hipStream_t stream)
{
    (void)in_sizes; (void)n_in; (void)out_size; (void)ws_size;
    const float* hidden = (const float*)d_in[0];
    const float* W      = (const float*)d_in[1];
    const float* bias   = (const float*)d_in[2];
    const float* st     = (const float*)d_in[3];
    const float* et     = (const float*)d_in[4];
    const float* trans  = (const float*)d_in[5];
    const int*   labels = (const int*)d_in[6];
    const int*   amask  = (const int*)d_in[7];

    float* out    = (float*)d_out;
    float* nll    = out;
    float* logits = out + 1;
    float* em     = out + 1 + EM_ELEMS;
    float* ws     = (float*)d_ws;

    emis_kernel<<<dim3(Bn*Tn/64), dim3(256), 0, stream>>>(hidden, W, bias, em);
    chunk_scan<<<dim3(2048), dim3(64), 0, stream>>>(em, labels, amask, st, et, trans, ws, logits);
    post_kernel<<<dim3(2*Bn), dim3(512), 0, stream>>>(em, labels, amask, st, et, trans, ws, logits);
    fin_kernel<<<dim3(1), dim3(64), 0, stream>>>(ws, nll);
}

// Round 22
// 71.295 us; speedup vs baseline: 1.6860x; 1.6860x over previous
//
#include <hip/hip_runtime.h>

#define Bn 64
#define Tn 512
#define Hn 768
#define Ln 21
#define EM_ELEMS (Bn*Tn*Ln)
#define NCH 16   // chunks per batch (32 real steps each)

// ws float offsets
#define DELTA_OFF 0      // [1024] per (b,c) NLL log-growth
#define LA0_OFF   1024   // [64]  log sum at t=0
#define W_OFF2    1088   // [64]  et-weighted final ratio
#define SCORE_OFF 1152   // [64]  gold score
#define TAG_OFF   1216   // [64]  final viterbi tag (int)

__device__ __forceinline__ float rl(float x, int i){
    return __int_as_float(__builtin_amdgcn_readlane(__float_as_int(x), i));
}

// 21 readlanes into 21 DISTINCT SGPRs in one asm block (pipelined, no SGPR reuse hazard)
// NOTE: loops containing this macro MUST stay rolled — 8x unrolling it miscompiled (r9/r10: inf).
#define READLANES(src, A) \
    asm volatile( \
        "v_readlane_b32 %0, %[v], 0\n\t" \
        "v_readlane_b32 %1, %[v], 1\n\t" \
        "v_readlane_b32 %2, %[v], 2\n\t" \
        "v_readlane_b32 %3, %[v], 3\n\t" \
        "v_readlane_b32 %4, %[v], 4\n\t" \
        "v_readlane_b32 %5, %[v], 5\n\t" \
        "v_readlane_b32 %6, %[v], 6\n\t" \
        "v_readlane_b32 %7, %[v], 7\n\t" \
        "v_readlane_b32 %8, %[v], 8\n\t" \
        "v_readlane_b32 %9, %[v], 9\n\t" \
        "v_readlane_b32 %10, %[v], 10\n\t" \
        "v_readlane_b32 %11, %[v], 11\n\t" \
        "v_readlane_b32 %12, %[v], 12\n\t" \
        "v_readlane_b32 %13, %[v], 13\n\t" \
        "v_readlane_b32 %14, %[v], 14\n\t" \
        "v_readlane_b32 %15, %[v], 15\n\t" \
        "v_readlane_b32 %16, %[v], 16\n\t" \
        "v_readlane_b32 %17, %[v], 17\n\t" \
        "v_readlane_b32 %18, %[v], 18\n\t" \
        "v_readlane_b32 %19, %[v], 19\n\t" \
        "v_readlane_b32 %20, %[v], 20\n\t" \
        : "=s"(A[0]),"=s"(A[1]),"=s"(A[2]),"=s"(A[3]),"=s"(A[4]), \
          "=s"(A[5]),"=s"(A[6]),"=s"(A[7]),"=s"(A[8]),"=s"(A[9]), \
          "=s"(A[10]),"=s"(A[11]),"=s"(A[12]),"=s"(A[13]),"=s"(A[14]), \
          "=s"(A[15]),"=s"(A[16]),"=s"(A[17]),"=s"(A[18]),"=s"(A[19]), \
          "=s"(A[20]) \
        : [v]"v"(src))

// viterbi warmup step body (r7 verbatim)
#define VIT_STEP(WORD, S) \
    float ec = e1; e1 = e2; \
    e2 = epr[0]; epr += Ln; \
    float A[21]; \
    READLANES(sc, A); \
    float v0=A[0]+trc[0],  v1=A[1]+trc[1],  v2=A[2]+trc[2]; \
    float v3=A[3]+trc[3],  v4=A[4]+trc[4],  v5=A[5]+trc[5]; \
    float v6=A[6]+trc[6],  v7=A[7]+trc[7],  v8=A[8]+trc[8]; \
    float v9=A[9]+trc[9],  v10=A[10]+trc[10],v11=A[11]+trc[11]; \
    float v12=A[12]+trc[12],v13=A[13]+trc[13],v14=A[14]+trc[14]; \
    float v15=A[15]+trc[15],v16=A[16]+trc[16],v17=A[17]+trc[17]; \
    float v18=A[18]+trc[18],v19=A[19]+trc[19],v20=A[20]+trc[20]; \
    float a0 = fmaxf(fmaxf(v0,v1),v2); \
    float a1 = fmaxf(fmaxf(v3,v4),v5); \
    float a2 = fmaxf(fmaxf(v6,v7),v8); \
    float a3 = fmaxf(fmaxf(v9,v10),v11); \
    float a4 = fmaxf(fmaxf(v12,v13),v14); \
    float a5 = fmaxf(fmaxf(v15,v16),v17); \
    float a6 = fmaxf(fmaxf(v18,v19),v20); \
    float b0 = fmaxf(fmaxf(a0,a1),a2); \
    float b1 = fmaxf(fmaxf(a3,a4),a5); \
    float best = fmaxf(fmaxf(b0,b1),a6); \
    float scn = best + ec; \
    int mc = (int)((WORD >> (S)) & 1ull); \
    sc = mc ? scn : sc;

// viterbi real step: VIT_STEP + backpointer emit (bitmask/__ffs code identical to old post recompute)
#define VIT_STEP_H(WORD, S, T) \
    float ec = e1; e1 = e2; \
    e2 = epr[0]; epr += Ln; \
    float A[21]; \
    READLANES(sc, A); \
    float v0=A[0]+trc[0],  v1=A[1]+trc[1],  v2=A[2]+trc[2]; \
    float v3=A[3]+trc[3],  v4=A[4]+trc[4],  v5=A[5]+trc[5]; \
    float v6=A[6]+trc[6],  v7=A[7]+trc[7],  v8=A[8]+trc[8]; \
    float v9=A[9]+trc[9],  v10=A[10]+trc[10],v11=A[11]+trc[11]; \
    float v12=A[12]+trc[12],v13=A[13]+trc[13],v14=A[14]+trc[14]; \
    float v15=A[15]+trc[15],v16=A[16]+trc[16],v17=A[17]+trc[17]; \
    float v18=A[18]+trc[18],v19=A[19]+trc[19],v20=A[20]+trc[20]; \
    float a0 = fmaxf(fmaxf(v0,v1),v2); \
    float a1 = fmaxf(fmaxf(v3,v4),v5); \
    float a2 = fmaxf(fmaxf(v6,v7),v8); \
    float a3 = fmaxf(fmaxf(v9,v10),v11); \
    float a4 = fmaxf(fmaxf(v12,v13),v14); \
    float a5 = fmaxf(fmaxf(v15,v16),v17); \
    float a6 = fmaxf(fmaxf(v18,v19),v20); \
    float b0 = fmaxf(fmaxf(a0,a1),a2); \
    float b1 = fmaxf(fmaxf(a3,a4),a5); \
    float best = fmaxf(fmaxf(b0,b1),a6); \
    float scn = best + ec; \
    int mc = (int)((WORD >> (S)) & 1ull); \
    unsigned bm = 0u; \
    bm |= (v0==best)?1u<<0:0u;  bm |= (v1==best)?1u<<1:0u;  bm |= (v2==best)?1u<<2:0u; \
    bm |= (v3==best)?1u<<3:0u;  bm |= (v4==best)?1u<<4:0u;  bm |= (v5==best)?1u<<5:0u; \
    bm |= (v6==best)?1u<<6:0u;  bm |= (v7==best)?1u<<7:0u;  bm |= (v8==best)?1u<<8:0u; \
    bm |= (v9==best)?1u<<9:0u;  bm |= (v10==best)?1u<<10:0u; bm |= (v11==best)?1u<<11:0u; \
    bm |= (v12==best)?1u<<12:0u; bm |= (v13==best)?1u<<13:0u; bm |= (v14==best)?1u<<14:0u; \
    bm |= (v15==best)?1u<<15:0u; bm |= (v16==best)?1u<<16:0u; bm |= (v17==best)?1u<<17:0u; \
    bm |= (v18==best)?1u<<18:0u; bm |= (v19==best)?1u<<19:0u; bm |= (v20==best)?1u<<20:0u; \
    int bpv = __ffs(bm) - 1; \
    int bps = mc ? bpv : j; \
    if (act) hg[(size_t)(T)*Ln + j] = (unsigned char)bps; \
    sc = mc ? scn : sc;

// NLL step body (r7 verbatim)
#define NLL_STEP(WORD, S) \
    float ec = e1; e1 = e2; \
    e2 = epr[0]; epr += Ln; \
    float pe = __expf(ec); \
    float A[21]; \
    READLANES(p, A); \
    float s0=0.f,s1=0.f,s2=0.f; \
    _Pragma("unroll") \
    for (int i=0;i<Ln;++i){ \
        if      (i%3==0) s0 = fmaf(A[i], Ec[i], s0); \
        else if (i%3==1) s1 = fmaf(A[i], Ec[i], s1); \
        else             s2 = fmaf(A[i], Ec[i], s2); \
    } \
    float pn = ((s0+s1)+s2) * pe; \
    int lc = (int)((WORD >> (S)) & 1ull); \
    p = lc ? pn : p; \
    if (((S) & 7) == 0){ \
        float p0 = rl(p, 0); \
        int e; frexpf(p0, &e); \
        p = ldexpf(p, -e); \
        M += (float)e * 0.6931471805599453f; \
    }

// ---------------- emissions = hidden @ W + b  (r14 proven form: split-K x4, readlane W) ----------------
__global__ __launch_bounds__(256) void emis_kernel(
    const float* __restrict__ hidden, const float* __restrict__ W,
    const float* __restrict__ bias, float* __restrict__ em)
{
    __shared__ float part[4][64][22];
    const int lane = threadIdx.x & 63;
    const int w    = threadIdx.x >> 6;
    const int row  = blockIdx.x*64 + lane;
    const int wb   = 64 + (lane < 20 ? lane : 19);
    const float4* h4 = (const float4*)(hidden + (size_t)row*Hn) + w*48;
    const float*  Wp = W + w*(192*Ln);
    float acc[Ln];
    #pragma unroll
    for (int j=0;j<Ln;++j) acc[j]=0.f;
    float4 hcur = h4[0];
    float Wa = Wp[lane], Wb2 = Wp[wb];
    for (int t=0;t<48;++t){
        float4 hn = hcur; float Wan = Wa, Wbn = Wb2;
        if (t<47){ hn = h4[t+1]; Wan = Wp[(t+1)*84+lane]; Wbn = Wp[(t+1)*84+wb]; }
        const float* hv = &hcur.x;
        #pragma unroll
        for (int c=0;c<4;++c){
            float x = hv[c];
            #pragma unroll
            for (int j=0;j<Ln;++j){
                const int idx = c*Ln+j;
                float wv = (idx<64) ? rl(Wa, idx) : rl(Wb2, idx-64);
                acc[j] = fmaf(x, wv, acc[j]);
            }
        }
        hcur=hn; Wa=Wan; Wb2=Wbn;
    }
    #pragma unroll
    for (int j=0;j<Ln;++j) part[w][lane][j] = acc[j];
    __syncthreads();
    float* ob = em + (size_t)blockIdx.x*64*Ln;
    for (int e=threadIdx.x; e<64*Ln; e+=256){
        int r = e/Ln, j = e-r*Ln;
        ob[e] = ((part[0][r][j]+part[1][r][j])+(part[2][r][j]+part[3][r][j])) + bias[j];
    }
}

// ---------------- chunk_scan: 2048 blocks x 64; blk<1024 viterbi chunk, else NLL chunk.
//   viterbi chunks emit hist bytes (backpointers) into the logits region.
__global__ __launch_bounds__(64) void chunk_scan(
    const float* __restrict__ em, const int* __restrict__ labels,
    const int* __restrict__ amask, const float* __restrict__ st,
    const float* __restrict__ et, const float* __restrict__ trans,
    float* __restrict__ ws, float* __restrict__ logits)
{
    __shared__ float em_s[66*Ln];        // staged rows [w0 .. tstart+31] + 2 pad

    const int mode = blockIdx.x >> 10;   // 0 viterbi, 1 nll
    const int idx  = blockIdx.x & 1023;
    const int b    = idx >> 4;
    const int c    = idx & (NCH-1);
    const int lane = threadIdx.x;
    const bool act = (lane < Ln);
    const int  j   = act ? lane : 0;

    const int tstart = c*32;
    const int WARM   = (c==0) ? 0 : 32;
    const int w0     = tstart - WARM;
    const int nrows  = WARM + 32;

    const float* emg = em + (size_t)b*Tn*Ln;
    for (int i=lane; i<nrows*Ln; i+=64) em_s[i] = emg[(size_t)w0*Ln + i];
    for (int i=lane; i<2*Ln; i+=64){
        int jj = (i < Ln) ? i : (i - Ln);
        em_s[nrows*Ln + i] = em_s[(nrows-1)*Ln + jj];
    }
    __syncthreads();

    if (mode == 0){
        const int* mk = amask + b*Tn;
        // global last unmasked index
        int last = -1;
        #pragma unroll
        for (int k=0;k<8;++k){ int mv = mk[k*64+lane]; if (mv) last = k*64+lane; }
        #pragma unroll
        for (int off=32; off>=1; off>>=1){ int o = __shfl_xor(last, off, 64); last = (o>last)?o:last; }
        const bool owner = (last >= tstart) && (last < tstart+32);

        unsigned long long word = __ballot(mk[w0 + lane] != 0);

        float trc[Ln];
        #pragma unroll
        for (int i=0;i<Ln;++i) trc[i] = trans[i*Ln + j];

        float sc;
        if (c==0) sc = act ? (st[j] + em_s[j]) : -1e30f;
        else      sc = act ? 0.f : -1e30f;

        unsigned char* hg = (unsigned char*)(logits + (size_t)b*Tn*Ln);  // hist bytes live here

        const float* epr = &em_s[Ln + j];
        float e1 = epr[0]; epr += Ln;
        float e2 = epr[0]; epr += Ln;

        if (c > 0){
            for (int s=1; s<32; ++s){        // warmup (no store)
                VIT_STEP(word, s)
            }
        }
        const int s0i = (c==0) ? 1 : 0;
        for (int s=s0i; s<32; ++s){          // real: advance + emit backpointer
            VIT_STEP_H(word, WARM + s, tstart + s)
        }
        if (owner){
            float val = act ? (sc + et[j]) : -1e30f;
            int   tix = act ? j : 1000;
            #pragma unroll
            for (int off=32; off>=1; off>>=1){
                float ov = __shfl_xor(val, off, 64);
                int   oi = __shfl_xor(tix, off, 64);
                if (ov > val || (ov==val && oi<tix)){ val=ov; tix=oi; }
            }
            if (lane==0) ((int*)(ws+TAG_OFF))[b] = tix;
        }
    } else {
        const int* lb = labels + b*Tn;
        int last = -1;
        #pragma unroll
        for (int k=0;k<8;++k){ int mv = (lb[k*64+lane] != -100) ? 1 : 0; if (mv) last = k*64+lane; }
        #pragma unroll
        for (int off=32; off>=1; off>>=1){ int o = __shfl_xor(last, off, 64); last = (o>last)?o:last; }
        const bool owner = (last >= tstart) && (last < tstart+32);

        unsigned long long word = __ballot(lb[w0 + lane] != -100);

        float Ec[Ln];
        #pragma unroll
        for (int i=0;i<Ln;++i) Ec[i] = __expf(trans[i*Ln + j]);

        float p, M = 0.f, La;
        if (c==0){
            p = act ? __expf(st[j] + em_s[j]) : 0.f;
            float sm = p;
            #pragma unroll
            for (int off=32; off>=1; off>>=1) sm += __shfl_xor(sm, off, 64);
            La = __logf(sm);                 // M=0 at init
        } else {
            p = act ? 1.f : 0.f;
            La = 0.f;                        // set after warmup
        }

        const float* epr = &em_s[Ln + j];
        float e1 = epr[0]; epr += Ln;
        float e2 = epr[0]; epr += Ln;

        if (c > 0){
            for (int s=1; s<32; ++s){        // warmup
                NLL_STEP(word, s)
            }
            float sm = act ? p : 0.f;
            #pragma unroll
            for (int off=32; off>=1; off>>=1) sm += __shfl_xor(sm, off, 64);
            La = M + __logf(sm);
        }
        const int s0i = (c==0) ? 1 : 0;
        for (int s=s0i; s<32; ++s){          // real
            NLL_STEP(word, WARM + s)
        }
        float sm = act ? p : 0.f;
        #pragma unroll
        for (int off=32; off>=1; off>>=1) sm += __shfl_xor(sm, off, 64);
        float Lb = M + __logf(sm);
        if (lane==0) (ws+DELTA_OFF)[b*NCH + c] = Lb - La;
        if (c==0 && lane==0) (ws+LA0_OFF)[b] = La;
        if (owner){
            float wsum = act ? (p * __expf(et[j])) : 0.f;
            #pragma unroll
            for (int off=32; off>=1; off>>=1) wsum += __shfl_xor(wsum, off, 64);
            if (lane==0) (ws+W_OFF2)[b] = __logf(wsum) - __logf(sm);
        }
    }
}

// ---------------- post: blocks 0..63 backtrack+logits (hist precomputed); 64..127 gold score ----------------
__global__ __launch_bounds__(512) void post_kernel(
    const float* __restrict__ em, const int* __restrict__ labels,
    const int* __restrict__ amask, const float* __restrict__ st,
    const float* __restrict__ et, const float* __restrict__ trans,
    float* __restrict__ ws, float* __restrict__ logits)
{
    const int b    = blockIdx.x & (Bn-1);
    const int mode = blockIdx.x >> 6;
    const int tid  = threadIdx.x;

    if (mode == 0){
        __shared__ unsigned char hist_s[Tn*Ln];
        __shared__ int lab_s[Tn];
        __shared__ int path_s[Tn];
        __shared__ unsigned char comp_s[64*Ln];
        __shared__ unsigned char ent_s[64];
        lab_s[tid] = amask[b*Tn + tid];
        const unsigned char* hg = (const unsigned char*)(logits + (size_t)b*Tn*Ln);
        for (int i=tid; i<Tn*Ln; i+=512) hist_s[i] = hg[i];
        __syncthreads();
        if (tid < 64){
            unsigned char cur[Ln];
            #pragma unroll
            for (int q=0;q<Ln;++q) cur[q] = (unsigned char)q;
            #pragma unroll
            for (int k=8;k>=1;--k){
                int ta = 8*tid + k;
                if (ta < Tn){
                    const unsigned char* hr = &hist_s[ta*Ln];
                    #pragma unroll
                    for (int q=0;q<Ln;++q) cur[q] = hr[cur[q]];
                }
            }
            #pragma unroll
            for (int q=0;q<Ln;++q) comp_s[tid*Ln+q] = cur[q];
        }
        __syncthreads();
        if (tid==0){
            int cg = ((const int*)(ws+TAG_OFF))[b];
            for (int l=63;l>=0;--l){ ent_s[l]=(unsigned char)cg; cg = comp_s[l*Ln+cg]; }
        }
        __syncthreads();
        if (tid < 64){
            int s = ent_s[tid];
            if (tid==63) path_s[Tn-1] = s;
            #pragma unroll
            for (int k=8;k>=1;--k){
                int ta = 8*tid + k;
                if (ta < Tn){ s = hist_s[ta*Ln+s]; path_s[ta-1] = s; }
            }
        }
        __syncthreads();   // all hist reads done; overwrite region with one-hot
        float* lg = logits + (size_t)b*Tn*Ln;
        for (int id2=tid; id2<Tn*Ln; id2+=512){
            int t = id2/Ln; int jj = id2 - t*Ln;
            lg[id2] = (lab_s[t] && path_s[t]==jj) ? 1.0f : 0.0f;
        }
    } else {
        __shared__ float red_s[8];
        __shared__ int  redc_s[8];
        const int* lb = labels + b*Tn;
        int labt = lb[tid];
        float term = 0.f;
        int c = (tid==0 || labt != -100) ? 1 : 0;
        if (tid>=1 && labt != -100){
            int lp = lb[tid-1]; if (lp<0) lp=0;
            term = trans[lp*Ln+labt] + em[((size_t)b*Tn+tid)*Ln + labt];
        }
        #pragma unroll
        for (int off=32; off>=1; off>>=1){
            term += __shfl_xor(term, off, 64);
            c    += __shfl_xor(c,    off, 64);
        }
        int w = tid>>6;
        if ((tid&63)==0){ red_s[w]=term; redc_s[w]=c; }
        __syncthreads();
        if (tid==0){
            float sum=0.f; int cnt=0;
            #pragma unroll
            for (int q=0;q<8;++q){ sum+=red_s[q]; cnt+=redc_s[q]; }
            int l0 = lb[0]; int tag0 = l0<0?0:l0;
            float score = st[tag0] + em[(size_t)b*Tn*Ln + tag0] + sum;
            int li = cnt-1; int ll = lb[li]; int lt = ll<0?0:ll;
            score += et[lt];
            (ws+SCORE_OFF)[b] = score;
        }
    }
}

// ---------------- finalize: nll = -mean(score - logZ) ----------------
__global__ __launch_bounds__(64) void fin_kernel(const float* __restrict__ ws,
                                                 float* __restrict__ out0)
{
    const int b = threadIdx.x;
    float logZ = (ws+LA0_OFF)[b] + (ws+W_OFF2)[b];
    #pragma unroll
    for (int c=0;c<NCH;++c) logZ += (ws+DELTA_OFF)[b*NCH + c];
    float v = (ws+SCORE_OFF)[b] - logZ;
    #pragma unroll
    for (int off=32; off>=1; off>>=1) v += __shfl_xor(v, off, 64);
    if (b==0) out0[0] = -(v * (1.0f/64.0f));
}

extern "C" void kernel_launch(void* const* d_in, const int* in_sizes, int n_in,
                              void* d_out, int out_size, void* d_ws, size_t ws_size,
                              hipStream_t stream)
{
    (void)in_sizes; (void)n_in; (void)out_size; (void)ws_size;
    const float* hidden = (const float*)d_in[0];
    const float* W      = (const float*)d_in[1];
    const float* bias   = (const float*)d_in[2];
    const float* st     = (const float*)d_in[3];
    const float* et     = (const float*)d_in[4];
    const float* trans  = (const float*)d_in[5];
    const int*   labels = (const int*)d_in[6];
    const int*   amask  = (const int*)d_in[7];

    float* out    = (float*)d_out;
    float* nll    = out;
    float* logits = out + 1;
    float* em     = out + 1 + EM_ELEMS;
    float* ws     = (float*)d_ws;

    emis_kernel<<<dim3(Bn*Tn/64), dim3(256), 0, stream>>>(hidden, W, bias, em);
    chunk_scan<<<dim3(2048), dim3(64), 0, stream>>>(em, labels, amask, st, et, trans, ws, logits);
    post_kernel<<<dim3(2*Bn), dim3(512), 0, stream>>>(em, labels, amask, st, et, trans, ws, logits);
    fin_kernel<<<dim3(1), dim3(64), 0, stream>>>(ws, nll);
}

// Round 23
// 65.619 us; speedup vs baseline: 1.8319x; 1.0865x over previous
//
#include <hip/hip_runtime.h>

#define Bn 64
#define Tn 512
#define Hn 768
#define Ln 21
#define EM_ELEMS (Bn*Tn*Ln)
#define NCH 16   // chunks per batch (32 real steps each)

// ws float offsets
#define DELTA_OFF 0      // [1024] per (b,c) NLL log-growth
#define LA0_OFF   1024   // [64]  log sum at t=0
#define W_OFF2    1088   // [64]  et-weighted final ratio
#define SCORE_OFF 1152   // [64]  gold score
#define TAG_OFF   1216   // [64]  final viterbi tag (int)

__device__ __forceinline__ float rl(float x, int i){
    return __int_as_float(__builtin_amdgcn_readlane(__float_as_int(x), i));
}

// 21 readlanes into 21 DISTINCT SGPRs in one asm block (pipelined, no SGPR reuse hazard)
// NOTE: loops containing this macro MUST stay rolled — 8x unrolling it miscompiled (r9/r10: inf).
#define READLANES(src, A) \
    asm volatile( \
        "v_readlane_b32 %0, %[v], 0\n\t" \
        "v_readlane_b32 %1, %[v], 1\n\t" \
        "v_readlane_b32 %2, %[v], 2\n\t" \
        "v_readlane_b32 %3, %[v], 3\n\t" \
        "v_readlane_b32 %4, %[v], 4\n\t" \
        "v_readlane_b32 %5, %[v], 5\n\t" \
        "v_readlane_b32 %6, %[v], 6\n\t" \
        "v_readlane_b32 %7, %[v], 7\n\t" \
        "v_readlane_b32 %8, %[v], 8\n\t" \
        "v_readlane_b32 %9, %[v], 9\n\t" \
        "v_readlane_b32 %10, %[v], 10\n\t" \
        "v_readlane_b32 %11, %[v], 11\n\t" \
        "v_readlane_b32 %12, %[v], 12\n\t" \
        "v_readlane_b32 %13, %[v], 13\n\t" \
        "v_readlane_b32 %14, %[v], 14\n\t" \
        "v_readlane_b32 %15, %[v], 15\n\t" \
        "v_readlane_b32 %16, %[v], 16\n\t" \
        "v_readlane_b32 %17, %[v], 17\n\t" \
        "v_readlane_b32 %18, %[v], 18\n\t" \
        "v_readlane_b32 %19, %[v], 19\n\t" \
        "v_readlane_b32 %20, %[v], 20\n\t" \
        : "=s"(A[0]),"=s"(A[1]),"=s"(A[2]),"=s"(A[3]),"=s"(A[4]), \
          "=s"(A[5]),"=s"(A[6]),"=s"(A[7]),"=s"(A[8]),"=s"(A[9]), \
          "=s"(A[10]),"=s"(A[11]),"=s"(A[12]),"=s"(A[13]),"=s"(A[14]), \
          "=s"(A[15]),"=s"(A[16]),"=s"(A[17]),"=s"(A[18]),"=s"(A[19]), \
          "=s"(A[20]) \
        : [v]"v"(src))

// viterbi warmup step body (r7 verbatim)
#define VIT_STEP(WORD, S) \
    float ec = e1; e1 = e2; \
    e2 = epr[0]; epr += Ln; \
    float A[21]; \
    READLANES(sc, A); \
    float v0=A[0]+trc[0],  v1=A[1]+trc[1],  v2=A[2]+trc[2]; \
    float v3=A[3]+trc[3],  v4=A[4]+trc[4],  v5=A[5]+trc[5]; \
    float v6=A[6]+trc[6],  v7=A[7]+trc[7],  v8=A[8]+trc[8]; \
    float v9=A[9]+trc[9],  v10=A[10]+trc[10],v11=A[11]+trc[11]; \
    float v12=A[12]+trc[12],v13=A[13]+trc[13],v14=A[14]+trc[14]; \
    float v15=A[15]+trc[15],v16=A[16]+trc[16],v17=A[17]+trc[17]; \
    float v18=A[18]+trc[18],v19=A[19]+trc[19],v20=A[20]+trc[20]; \
    float a0 = fmaxf(fmaxf(v0,v1),v2); \
    float a1 = fmaxf(fmaxf(v3,v4),v5); \
    float a2 = fmaxf(fmaxf(v6,v7),v8); \
    float a3 = fmaxf(fmaxf(v9,v10),v11); \
    float a4 = fmaxf(fmaxf(v12,v13),v14); \
    float a5 = fmaxf(fmaxf(v15,v16),v17); \
    float a6 = fmaxf(fmaxf(v18,v19),v20); \
    float b0 = fmaxf(fmaxf(a0,a1),a2); \
    float b1 = fmaxf(fmaxf(a3,a4),a5); \
    float best = fmaxf(fmaxf(b0,b1),a6); \
    float scn = best + ec; \
    int mc = (int)((WORD >> (S)) & 1ull); \
    sc = mc ? scn : sc;

// viterbi real step: VIT_STEP + backpointer emit (bitmask/__ffs identical to old post recompute)
#define VIT_STEP_H(WORD, S, T) \
    float ec = e1; e1 = e2; \
    e2 = epr[0]; epr += Ln; \
    float A[21]; \
    READLANES(sc, A); \
    float v0=A[0]+trc[0],  v1=A[1]+trc[1],  v2=A[2]+trc[2]; \
    float v3=A[3]+trc[3],  v4=A[4]+trc[4],  v5=A[5]+trc[5]; \
    float v6=A[6]+trc[6],  v7=A[7]+trc[7],  v8=A[8]+trc[8]; \
    float v9=A[9]+trc[9],  v10=A[10]+trc[10],v11=A[11]+trc[11]; \
    float v12=A[12]+trc[12],v13=A[13]+trc[13],v14=A[14]+trc[14]; \
    float v15=A[15]+trc[15],v16=A[16]+trc[16],v17=A[17]+trc[17]; \
    float v18=A[18]+trc[18],v19=A[19]+trc[19],v20=A[20]+trc[20]; \
    float a0 = fmaxf(fmaxf(v0,v1),v2); \
    float a1 = fmaxf(fmaxf(v3,v4),v5); \
    float a2 = fmaxf(fmaxf(v6,v7),v8); \
    float a3 = fmaxf(fmaxf(v9,v10),v11); \
    float a4 = fmaxf(fmaxf(v12,v13),v14); \
    float a5 = fmaxf(fmaxf(v15,v16),v17); \
    float a6 = fmaxf(fmaxf(v18,v19),v20); \
    float b0 = fmaxf(fmaxf(a0,a1),a2); \
    float b1 = fmaxf(fmaxf(a3,a4),a5); \
    float best = fmaxf(fmaxf(b0,b1),a6); \
    float scn = best + ec; \
    int mc = (int)((WORD >> (S)) & 1ull); \
    unsigned bm = 0u; \
    bm |= (v0==best)?1u<<0:0u;  bm |= (v1==best)?1u<<1:0u;  bm |= (v2==best)?1u<<2:0u; \
    bm |= (v3==best)?1u<<3:0u;  bm |= (v4==best)?1u<<4:0u;  bm |= (v5==best)?1u<<5:0u; \
    bm |= (v6==best)?1u<<6:0u;  bm |= (v7==best)?1u<<7:0u;  bm |= (v8==best)?1u<<8:0u; \
    bm |= (v9==best)?1u<<9:0u;  bm |= (v10==best)?1u<<10:0u; bm |= (v11==best)?1u<<11:0u; \
    bm |= (v12==best)?1u<<12:0u; bm |= (v13==best)?1u<<13:0u; bm |= (v14==best)?1u<<14:0u; \
    bm |= (v15==best)?1u<<15:0u; bm |= (v16==best)?1u<<16:0u; bm |= (v17==best)?1u<<17:0u; \
    bm |= (v18==best)?1u<<18:0u; bm |= (v19==best)?1u<<19:0u; bm |= (v20==best)?1u<<20:0u; \
    int bpv = __ffs(bm) - 1; \
    int bps = mc ? bpv : j; \
    if (act) hg[(size_t)(T)*Ln + j] = (unsigned char)bps; \
    sc = mc ? scn : sc;

// NLL step body (r7 verbatim)
#define NLL_STEP(WORD, S) \
    float ec = e1; e1 = e2; \
    e2 = epr[0]; epr += Ln; \
    float pe = __expf(ec); \
    float A[21]; \
    READLANES(p, A); \
    float s0=0.f,s1=0.f,s2=0.f; \
    _Pragma("unroll") \
    for (int i=0;i<Ln;++i){ \
        if      (i%3==0) s0 = fmaf(A[i], Ec[i], s0); \
        else if (i%3==1) s1 = fmaf(A[i], Ec[i], s1); \
        else             s2 = fmaf(A[i], Ec[i], s2); \
    } \
    float pn = ((s0+s1)+s2) * pe; \
    int lc = (int)((WORD >> (S)) & 1ull); \
    p = lc ? pn : p; \
    if (((S) & 7) == 0){ \
        float p0 = rl(p, 0); \
        int e; frexpf(p0, &e); \
        p = ldexpf(p, -e); \
        M += (float)e * 0.6931471805599453f; \
    }

// ---------------- emissions = hidden @ W + b  (split-K x4, readlane W, batch-4 line loads) ----------------
__global__ __launch_bounds__(256) void emis_kernel(
    const float* __restrict__ hidden, const float* __restrict__ W,
    const float* __restrict__ bias, float* __restrict__ em)
{
    __shared__ float part[4][64][22];
    const int lane = threadIdx.x & 63;
    const int w    = threadIdx.x >> 6;
    const int row  = blockIdx.x*64 + lane;
    const int wb   = 64 + (lane < 20 ? lane : 19);
    const float4* h4 = (const float4*)(hidden + (size_t)row*Hn) + w*48;
    const float*  Wp = W + w*(192*Ln);
    float acc[Ln];
    #pragma unroll
    for (int j=0;j<Ln;++j) acc[j]=0.f;
    for (int tb=0; tb<12; ++tb){
        float4 hb[4];
        float Wav[4], Wbv[4];
        #pragma unroll
        for (int q=0;q<4;++q){
            hb[q]  = h4[tb*4+q];                 // 4 float4 of ONE 64B line: 1 miss serves 4 bodies
            Wav[q] = Wp[(tb*4+q)*84+lane];
            Wbv[q] = Wp[(tb*4+q)*84+wb];
        }
        #pragma unroll
        for (int q=0;q<4;++q){
            const float* hv = &hb[q].x;
            #pragma unroll
            for (int c=0;c<4;++c){
                float x = hv[c];
                #pragma unroll
                for (int j=0;j<Ln;++j){
                    const int idx = c*Ln+j;
                    float wv = (idx<64) ? rl(Wav[q], idx) : rl(Wbv[q], idx-64);
                    acc[j] = fmaf(x, wv, acc[j]);
                }
            }
        }
    }
    #pragma unroll
    for (int j=0;j<Ln;++j) part[w][lane][j] = acc[j];
    __syncthreads();
    float* ob = em + (size_t)blockIdx.x*64*Ln;
    for (int e=threadIdx.x; e<64*Ln; e+=256){
        int r = e/Ln, j = e-r*Ln;
        ob[e] = ((part[0][r][j]+part[1][r][j])+(part[2][r][j]+part[3][r][j])) + bias[j];
    }
}

// ---------------- chunk_scan: 2048 blocks x 64; blk<1024 viterbi chunk, else NLL chunk.
//   viterbi chunks emit hist bytes (backpointers) into the logits region.
__global__ __launch_bounds__(64) void chunk_scan(
    const float* __restrict__ em, const int* __restrict__ labels,
    const int* __restrict__ amask, const float* __restrict__ st,
    const float* __restrict__ et, const float* __restrict__ trans,
    float* __restrict__ ws, float* __restrict__ logits)
{
    __shared__ float em_s[66*Ln];        // staged rows [w0 .. tstart+31] + 2 pad

    const int mode = blockIdx.x >> 10;   // 0 viterbi, 1 nll
    const int idx  = blockIdx.x & 1023;
    const int b    = idx >> 4;
    const int c    = idx & (NCH-1);
    const int lane = threadIdx.x;
    const bool act = (lane < Ln);
    const int  j   = act ? lane : 0;

    const int tstart = c*32;
    const int WARM   = (c==0) ? 0 : 32;
    const int w0     = tstart - WARM;
    const int nrows  = WARM + 32;

    const float* emg = em + (size_t)b*Tn*Ln;
    for (int i=lane; i<nrows*Ln; i+=64) em_s[i] = emg[(size_t)w0*Ln + i];
    for (int i=lane; i<2*Ln; i+=64){
        int jj = (i < Ln) ? i : (i - Ln);
        em_s[nrows*Ln + i] = em_s[(nrows-1)*Ln + jj];
    }
    __syncthreads();

    if (mode == 0){
        const int* mk = amask + b*Tn;
        // global last unmasked index
        int last = -1;
        #pragma unroll
        for (int k=0;k<8;++k){ int mv = mk[k*64+lane]; if (mv) last = k*64+lane; }
        #pragma unroll
        for (int off=32; off>=1; off>>=1){ int o = __shfl_xor(last, off, 64); last = (o>last)?o:last; }
        const bool owner = (last >= tstart) && (last < tstart+32);

        unsigned long long word = __ballot(mk[w0 + lane] != 0);

        float trc[Ln];
        #pragma unroll
        for (int i=0;i<Ln;++i) trc[i] = trans[i*Ln + j];

        float sc;
        if (c==0) sc = act ? (st[j] + em_s[j]) : -1e30f;
        else      sc = act ? 0.f : -1e30f;

        unsigned char* hg = (unsigned char*)(logits + (size_t)b*Tn*Ln);  // hist bytes live here

        const float* epr = &em_s[Ln + j];
        float e1 = epr[0]; epr += Ln;
        float e2 = epr[0]; epr += Ln;

        if (c > 0){
            for (int s=1; s<32; ++s){        // warmup (no store)
                VIT_STEP(word, s)
            }
        }
        const int s0i = (c==0) ? 1 : 0;
        for (int s=s0i; s<32; ++s){          // real: advance + emit backpointer
            VIT_STEP_H(word, WARM + s, tstart + s)
        }
        if (owner){
            float val = act ? (sc + et[j]) : -1e30f;
            int   tix = act ? j : 1000;
            #pragma unroll
            for (int off=32; off>=1; off>>=1){
                float ov = __shfl_xor(val, off, 64);
                int   oi = __shfl_xor(tix, off, 64);
                if (ov > val || (ov==val && oi<tix)){ val=ov; tix=oi; }
            }
            if (lane==0) ((int*)(ws+TAG_OFF))[b] = tix;
        }
    } else {
        const int* lb = labels + b*Tn;
        int last = -1;
        #pragma unroll
        for (int k=0;k<8;++k){ int mv = (lb[k*64+lane] != -100) ? 1 : 0; if (mv) last = k*64+lane; }
        #pragma unroll
        for (int off=32; off>=1; off>>=1){ int o = __shfl_xor(last, off, 64); last = (o>last)?o:last; }
        const bool owner = (last >= tstart) && (last < tstart+32);

        unsigned long long word = __ballot(lb[w0 + lane] != -100);

        float Ec[Ln];
        #pragma unroll
        for (int i=0;i<Ln;++i) Ec[i] = __expf(trans[i*Ln + j]);

        float p, M = 0.f, La;
        if (c==0){
            p = act ? __expf(st[j] + em_s[j]) : 0.f;
            float sm = p;
            #pragma unroll
            for (int off=32; off>=1; off>>=1) sm += __shfl_xor(sm, off, 64);
            La = __logf(sm);                 // M=0 at init
        } else {
            p = act ? 1.f : 0.f;
            La = 0.f;                        // set after warmup
        }

        const float* epr = &em_s[Ln + j];
        float e1 = epr[0]; epr += Ln;
        float e2 = epr[0]; epr += Ln;

        if (c > 0){
            for (int s=1; s<32; ++s){        // warmup
                NLL_STEP(word, s)
            }
            float sm = act ? p : 0.f;
            #pragma unroll
            for (int off=32; off>=1; off>>=1) sm += __shfl_xor(sm, off, 64);
            La = M + __logf(sm);
        }
        const int s0i = (c==0) ? 1 : 0;
        for (int s=s0i; s<32; ++s){          // real
            NLL_STEP(word, WARM + s)
        }
        float sm = act ? p : 0.f;
        #pragma unroll
        for (int off=32; off>=1; off>>=1) sm += __shfl_xor(sm, off, 64);
        float Lb = M + __logf(sm);
        if (lane==0) (ws+DELTA_OFF)[b*NCH + c] = Lb - La;
        if (c==0 && lane==0) (ws+LA0_OFF)[b] = La;
        if (owner){
            float wsum = act ? (p * __expf(et[j])) : 0.f;
            #pragma unroll
            for (int off=32; off>=1; off>>=1) wsum += __shfl_xor(wsum, off, 64);
            if (lane==0) (ws+W_OFF2)[b] = __logf(wsum) - __logf(sm);
        }
    }
}

// ---------------- post: blocks 0..63 backtrack+logits (hist precomputed); 64..127 gold score ----------------
__global__ __launch_bounds__(512) void post_kernel(
    const float* __restrict__ em, const int* __restrict__ labels,
    const int* __restrict__ amask, const float* __restrict__ st,
    const float* __restrict__ et, const float* __restrict__ trans,
    float* __restrict__ ws, float* __restrict__ logits)
{
    const int b    = blockIdx.x & (Bn-1);
    const int mode = blockIdx.x >> 6;
    const int tid  = threadIdx.x;

    if (mode == 0){
        __shared__ unsigned char hist_s[Tn*Ln];
        __shared__ int lab_s[Tn];
        __shared__ int path_s[Tn];
        __shared__ unsigned char comp_s[64*Ln];
        __shared__ unsigned char ent_s[64];
        lab_s[tid] = amask[b*Tn + tid];
        const unsigned char* hg = (const unsigned char*)(logits + (size_t)b*Tn*Ln);
        for (int i=tid; i<Tn*Ln; i+=512) hist_s[i] = hg[i];
        __syncthreads();
        if (tid < 64){
            unsigned char cur[Ln];
            #pragma unroll
            for (int q=0;q<Ln;++q) cur[q] = (unsigned char)q;
            #pragma unroll
            for (int k=8;k>=1;--k){
                int ta = 8*tid + k;
                if (ta < Tn){
                    const unsigned char* hr = &hist_s[ta*Ln];
                    #pragma unroll
                    for (int q=0;q<Ln;++q) cur[q] = hr[cur[q]];
                }
            }
            #pragma unroll
            for (int q=0;q<Ln;++q) comp_s[tid*Ln+q] = cur[q];
        }
        __syncthreads();
        if (tid==0){
            int cg = ((const int*)(ws+TAG_OFF))[b];
            for (int l=63;l>=0;--l){ ent_s[l]=(unsigned char)cg; cg = comp_s[l*Ln+cg]; }
        }
        __syncthreads();
        if (tid < 64){
            int s = ent_s[tid];
            if (tid==63) path_s[Tn-1] = s;
            #pragma unroll
            for (int k=8;k>=1;--k){
                int ta = 8*tid + k;
                if (ta < Tn){ s = hist_s[ta*Ln+s]; path_s[ta-1] = s; }
            }
        }
        __syncthreads();   // all hist reads done; overwrite region with one-hot
        float* lg = logits + (size_t)b*Tn*Ln;
        for (int id2=tid; id2<Tn*Ln; id2+=512){
            int t = id2/Ln; int jj = id2 - t*Ln;
            lg[id2] = (lab_s[t] && path_s[t]==jj) ? 1.0f : 0.0f;
        }
    } else {
        __shared__ float red_s[8];
        __shared__ int  redc_s[8];
        const int* lb = labels + b*Tn;
        int labt = lb[tid];
        float term = 0.f;
        int c = (tid==0 || labt != -100) ? 1 : 0;
        if (tid>=1 && labt != -100){
            int lp = lb[tid-1]; if (lp<0) lp=0;
            term = trans[lp*Ln+labt] + em[((size_t)b*Tn+tid)*Ln + labt];
        }
        #pragma unroll
        for (int off=32; off>=1; off>>=1){
            term += __shfl_xor(term, off, 64);
            c    += __shfl_xor(c,    off, 64);
        }
        int w = tid>>6;
        if ((tid&63)==0){ red_s[w]=term; redc_s[w]=c; }
        __syncthreads();
        if (tid==0){
            float sum=0.f; int cnt=0;
            #pragma unroll
            for (int q=0;q<8;++q){ sum+=red_s[q]; cnt+=redc_s[q]; }
            int l0 = lb[0]; int tag0 = l0<0?0:l0;
            float score = st[tag0] + em[(size_t)b*Tn*Ln + tag0] + sum;
            int li = cnt-1; int ll = lb[li]; int lt = ll<0?0:ll;
            score += et[lt];
            (ws+SCORE_OFF)[b] = score;
        }
    }
}

// ---------------- finalize: nll = -mean(score - logZ) ----------------
__global__ __launch_bounds__(64) void fin_kernel(const float* __restrict__ ws,
                                                 float* __restrict__ out0)
{
    const int b = threadIdx.x;
    float logZ = (ws+LA0_OFF)[b] + (ws+W_OFF2)[b];
    #pragma unroll
    for (int c=0;c<NCH;++c) logZ += (ws+DELTA_OFF)[b*NCH + c];
    float v = (ws+SCORE_OFF)[b] - logZ;
    #pragma unroll
    for (int off=32; off>=1; off>>=1) v += __shfl_xor(v, off, 64);
    if (b==0) out0[0] = -(v * (1.0f/64.0f));
}

extern "C" void kernel_launch(void* const* d_in, const int* in_sizes, int n_in,
                              void* d_out, int out_size, void* d_ws, size_t ws_size,
                              hipStream_t stream)
{
    (void)in_sizes; (void)n_in; (void)out_size; (void)ws_size;
    const float* hidden = (const float*)d_in[0];
    const float* W      = (const float*)d_in[1];
    const float* bias   = (const float*)d_in[2];
    const float* st     = (const float*)d_in[3];
    const float* et     = (const float*)d_in[4];
    const float* trans  = (const float*)d_in[5];
    const int*   labels = (const int*)d_in[6];
    const int*   amask  = (const int*)d_in[7];

    float* out    = (float*)d_out;
    float* nll    = out;
    float* logits = out + 1;
    float* em     = out + 1 + EM_ELEMS;
    float* ws     = (float*)d_ws;

    emis_kernel<<<dim3(Bn*Tn/64), dim3(256), 0, stream>>>(hidden, W, bias, em);
    chunk_scan<<<dim3(2048), dim3(64), 0, stream>>>(em, labels, amask, st, et, trans, ws, logits);
    post_kernel<<<dim3(2*Bn), dim3(512), 0, stream>>>(em, labels, amask, st, et, trans, ws, logits);
    fin_kernel<<<dim3(1), dim3(64), 0, stream>>>(ws, nll);
}

// Round 24
// 64.911 us; speedup vs baseline: 1.8518x; 1.0109x over previous
//
#include <hip/hip_runtime.h>

#define Bn 64
#define Tn 512
#define Hn 768
#define Ln 21
#define EM_ELEMS (Bn*Tn*Ln)
#define NCH 16   // chunks per batch (32 real steps each)

// ws float offsets
#define DELTA_OFF 0      // [1024] per (b,c) NLL log-growth
#define LA0_OFF   1024   // [64]  log sum at t=0
#define W_OFF2    1088   // [64]  et-weighted final ratio
#define SCORE_OFF 1152   // [64]  gold score
#define TAG_OFF   1216   // [64]  final viterbi tag (int)

__device__ __forceinline__ float rl(float x, int i){
    return __int_as_float(__builtin_amdgcn_readlane(__float_as_int(x), i));
}

// 21 readlanes into 21 DISTINCT SGPRs in one asm block (pipelined, no SGPR reuse hazard)
// NOTE: loops containing this macro MUST stay rolled in the scan — 8x unrolling it miscompiled (r9/r10).
#define READLANES(src, A) \
    asm volatile( \
        "v_readlane_b32 %0, %[v], 0\n\t" \
        "v_readlane_b32 %1, %[v], 1\n\t" \
        "v_readlane_b32 %2, %[v], 2\n\t" \
        "v_readlane_b32 %3, %[v], 3\n\t" \
        "v_readlane_b32 %4, %[v], 4\n\t" \
        "v_readlane_b32 %5, %[v], 5\n\t" \
        "v_readlane_b32 %6, %[v], 6\n\t" \
        "v_readlane_b32 %7, %[v], 7\n\t" \
        "v_readlane_b32 %8, %[v], 8\n\t" \
        "v_readlane_b32 %9, %[v], 9\n\t" \
        "v_readlane_b32 %10, %[v], 10\n\t" \
        "v_readlane_b32 %11, %[v], 11\n\t" \
        "v_readlane_b32 %12, %[v], 12\n\t" \
        "v_readlane_b32 %13, %[v], 13\n\t" \
        "v_readlane_b32 %14, %[v], 14\n\t" \
        "v_readlane_b32 %15, %[v], 15\n\t" \
        "v_readlane_b32 %16, %[v], 16\n\t" \
        "v_readlane_b32 %17, %[v], 17\n\t" \
        "v_readlane_b32 %18, %[v], 18\n\t" \
        "v_readlane_b32 %19, %[v], 19\n\t" \
        "v_readlane_b32 %20, %[v], 20\n\t" \
        : "=s"(A[0]),"=s"(A[1]),"=s"(A[2]),"=s"(A[3]),"=s"(A[4]), \
          "=s"(A[5]),"=s"(A[6]),"=s"(A[7]),"=s"(A[8]),"=s"(A[9]), \
          "=s"(A[10]),"=s"(A[11]),"=s"(A[12]),"=s"(A[13]),"=s"(A[14]), \
          "=s"(A[15]),"=s"(A[16]),"=s"(A[17]),"=s"(A[18]),"=s"(A[19]), \
          "=s"(A[20]) \
        : [v]"v"(src))

// viterbi warmup step body (r7 verbatim)
#define VIT_STEP(WORD, S) \
    float ec = e1; e1 = e2; \
    e2 = epr[0]; epr += Ln; \
    float A[21]; \
    READLANES(sc, A); \
    float v0=A[0]+trc[0],  v1=A[1]+trc[1],  v2=A[2]+trc[2]; \
    float v3=A[3]+trc[3],  v4=A[4]+trc[4],  v5=A[5]+trc[5]; \
    float v6=A[6]+trc[6],  v7=A[7]+trc[7],  v8=A[8]+trc[8]; \
    float v9=A[9]+trc[9],  v10=A[10]+trc[10],v11=A[11]+trc[11]; \
    float v12=A[12]+trc[12],v13=A[13]+trc[13],v14=A[14]+trc[14]; \
    float v15=A[15]+trc[15],v16=A[16]+trc[16],v17=A[17]+trc[17]; \
    float v18=A[18]+trc[18],v19=A[19]+trc[19],v20=A[20]+trc[20]; \
    float a0 = fmaxf(fmaxf(v0,v1),v2); \
    float a1 = fmaxf(fmaxf(v3,v4),v5); \
    float a2 = fmaxf(fmaxf(v6,v7),v8); \
    float a3 = fmaxf(fmaxf(v9,v10),v11); \
    float a4 = fmaxf(fmaxf(v12,v13),v14); \
    float a5 = fmaxf(fmaxf(v15,v16),v17); \
    float a6 = fmaxf(fmaxf(v18,v19),v20); \
    float b0 = fmaxf(fmaxf(a0,a1),a2); \
    float b1 = fmaxf(fmaxf(a3,a4),a5); \
    float best = fmaxf(fmaxf(b0,b1),a6); \
    float scn = best + ec; \
    int mc = (int)((WORD >> (S)) & 1ull); \
    sc = mc ? scn : sc;

// viterbi real step: VIT_STEP + backpointer emit (bitmask/__ffs identical to old post recompute)
#define VIT_STEP_H(WORD, S, T) \
    float ec = e1; e1 = e2; \
    e2 = epr[0]; epr += Ln; \
    float A[21]; \
    READLANES(sc, A); \
    float v0=A[0]+trc[0],  v1=A[1]+trc[1],  v2=A[2]+trc[2]; \
    float v3=A[3]+trc[3],  v4=A[4]+trc[4],  v5=A[5]+trc[5]; \
    float v6=A[6]+trc[6],  v7=A[7]+trc[7],  v8=A[8]+trc[8]; \
    float v9=A[9]+trc[9],  v10=A[10]+trc[10],v11=A[11]+trc[11]; \
    float v12=A[12]+trc[12],v13=A[13]+trc[13],v14=A[14]+trc[14]; \
    float v15=A[15]+trc[15],v16=A[16]+trc[16],v17=A[17]+trc[17]; \
    float v18=A[18]+trc[18],v19=A[19]+trc[19],v20=A[20]+trc[20]; \
    float a0 = fmaxf(fmaxf(v0,v1),v2); \
    float a1 = fmaxf(fmaxf(v3,v4),v5); \
    float a2 = fmaxf(fmaxf(v6,v7),v8); \
    float a3 = fmaxf(fmaxf(v9,v10),v11); \
    float a4 = fmaxf(fmaxf(v12,v13),v14); \
    float a5 = fmaxf(fmaxf(v15,v16),v17); \
    float a6 = fmaxf(fmaxf(v18,v19),v20); \
    float b0 = fmaxf(fmaxf(a0,a1),a2); \
    float b1 = fmaxf(fmaxf(a3,a4),a5); \
    float best = fmaxf(fmaxf(b0,b1),a6); \
    float scn = best + ec; \
    int mc = (int)((WORD >> (S)) & 1ull); \
    unsigned bm = 0u; \
    bm |= (v0==best)?1u<<0:0u;  bm |= (v1==best)?1u<<1:0u;  bm |= (v2==best)?1u<<2:0u; \
    bm |= (v3==best)?1u<<3:0u;  bm |= (v4==best)?1u<<4:0u;  bm |= (v5==best)?1u<<5:0u; \
    bm |= (v6==best)?1u<<6:0u;  bm |= (v7==best)?1u<<7:0u;  bm |= (v8==best)?1u<<8:0u; \
    bm |= (v9==best)?1u<<9:0u;  bm |= (v10==best)?1u<<10:0u; bm |= (v11==best)?1u<<11:0u; \
    bm |= (v12==best)?1u<<12:0u; bm |= (v13==best)?1u<<13:0u; bm |= (v14==best)?1u<<14:0u; \
    bm |= (v15==best)?1u<<15:0u; bm |= (v16==best)?1u<<16:0u; bm |= (v17==best)?1u<<17:0u; \
    bm |= (v18==best)?1u<<18:0u; bm |= (v19==best)?1u<<19:0u; bm |= (v20==best)?1u<<20:0u; \
    int bpv = __ffs(bm) - 1; \
    int bps = mc ? bpv : j; \
    if (act) hg[(size_t)(T)*Ln + j] = (unsigned char)bps; \
    sc = mc ? scn : sc;

// NLL step body (r7 verbatim)
#define NLL_STEP(WORD, S) \
    float ec = e1; e1 = e2; \
    e2 = epr[0]; epr += Ln; \
    float pe = __expf(ec); \
    float A[21]; \
    READLANES(p, A); \
    float s0=0.f,s1=0.f,s2=0.f; \
    _Pragma("unroll") \
    for (int i=0;i<Ln;++i){ \
        if      (i%3==0) s0 = fmaf(A[i], Ec[i], s0); \
        else if (i%3==1) s1 = fmaf(A[i], Ec[i], s1); \
        else             s2 = fmaf(A[i], Ec[i], s2); \
    } \
    float pn = ((s0+s1)+s2) * pe; \
    int lc = (int)((WORD >> (S)) & 1ull); \
    p = lc ? pn : p; \
    if (((S) & 7) == 0){ \
        float p0 = rl(p, 0); \
        int e; frexpf(p0, &e); \
        p = ldexpf(p, -e); \
        M += (float)e * 0.6931471805599453f; \
    }

// ---------------- emissions = hidden @ W + b  (split-K x4; W transposed-col + pipelined READLANES) ----------------
__global__ __launch_bounds__(256) void emis_kernel(
    const float* __restrict__ hidden, const float* __restrict__ W,
    const float* __restrict__ bias, float* __restrict__ em)
{
    __shared__ float part[4][64][22];
    const int lane = threadIdx.x & 63;
    const int w    = threadIdx.x >> 6;
    const int row  = blockIdx.x*64 + lane;
    const int cl   = (lane < 21) ? lane : 20;     // clamped col for W loads (lanes>20 unused)
    const float4* h4 = (const float4*)(hidden + (size_t)row*Hn) + w*48;
    const float*  Wc = W + (size_t)(w*192)*Ln;    // this wave's k-range, row-major [192][21]
    float acc[Ln];
    #pragma unroll
    for (int j=0;j<Ln;++j) acc[j]=0.f;
    for (int tb=0; tb<12; ++tb){
        float4 hb[4];
        float Wk[16];
        #pragma unroll
        for (int q=0;q<4;++q) hb[q] = h4[tb*4+q];          // one 64B line per thread
        #pragma unroll
        for (int kk=0;kk<16;++kk) Wk[kk] = Wc[(size_t)(tb*16+kk)*Ln + cl];  // W[k][j] in lane j
        #pragma unroll
        for (int q=0;q<4;++q){
            const float* hv = &hb[q].x;
            #pragma unroll
            for (int c=0;c<4;++c){
                float x = hv[c];
                float A[21];
                READLANES(Wk[q*4+c], A);                    // 21 pipelined rl -> 21 SGPRs
                #pragma unroll
                for (int j=0;j<Ln;++j)
                    acc[j] = fmaf(x, A[j], acc[j]);
            }
        }
    }
    #pragma unroll
    for (int j=0;j<Ln;++j) part[w][lane][j] = acc[j];
    __syncthreads();
    float* ob = em + (size_t)blockIdx.x*64*Ln;
    for (int e=threadIdx.x; e<64*Ln; e+=256){
        int r = e/Ln, j = e-r*Ln;
        ob[e] = ((part[0][r][j]+part[1][r][j])+(part[2][r][j]+part[3][r][j])) + bias[j];
    }
}

// ---------------- chunk_scan: 2048 blocks x 64; blk<1024 viterbi chunk, else NLL chunk.
//   viterbi chunks emit hist bytes (backpointers) into the logits region.
__global__ __launch_bounds__(64) void chunk_scan(
    const float* __restrict__ em, const int* __restrict__ labels,
    const int* __restrict__ amask, const float* __restrict__ st,
    const float* __restrict__ et, const float* __restrict__ trans,
    float* __restrict__ ws, float* __restrict__ logits)
{
    __shared__ float em_s[66*Ln];        // staged rows [w0 .. tstart+31] + 2 pad

    const int mode = blockIdx.x >> 10;   // 0 viterbi, 1 nll
    const int idx  = blockIdx.x & 1023;
    const int b    = idx >> 4;
    const int c    = idx & (NCH-1);
    const int lane = threadIdx.x;
    const bool act = (lane < Ln);
    const int  j   = act ? lane : 0;

    const int tstart = c*32;
    const int WARM   = (c==0) ? 0 : 32;
    const int w0     = tstart - WARM;
    const int nrows  = WARM + 32;

    const float* emg = em + (size_t)b*Tn*Ln;
    for (int i=lane; i<nrows*Ln; i+=64) em_s[i] = emg[(size_t)w0*Ln + i];
    for (int i=lane; i<2*Ln; i+=64){
        int jj = (i < Ln) ? i : (i - Ln);
        em_s[nrows*Ln + i] = em_s[(nrows-1)*Ln + jj];
    }
    __syncthreads();

    if (mode == 0){
        const int* mk = amask + b*Tn;
        // global last unmasked index
        int last = -1;
        #pragma unroll
        for (int k=0;k<8;++k){ int mv = mk[k*64+lane]; if (mv) last = k*64+lane; }
        #pragma unroll
        for (int off=32; off>=1; off>>=1){ int o = __shfl_xor(last, off, 64); last = (o>last)?o:last; }
        const bool owner = (last >= tstart) && (last < tstart+32);

        unsigned long long word = __ballot(mk[w0 + lane] != 0);

        float trc[Ln];
        #pragma unroll
        for (int i=0;i<Ln;++i) trc[i] = trans[i*Ln + j];

        float sc;
        if (c==0) sc = act ? (st[j] + em_s[j]) : -1e30f;
        else      sc = act ? 0.f : -1e30f;

        unsigned char* hg = (unsigned char*)(logits + (size_t)b*Tn*Ln);  // hist bytes live here

        const float* epr = &em_s[Ln + j];
        float e1 = epr[0]; epr += Ln;
        float e2 = epr[0]; epr += Ln;

        if (c > 0){
            for (int s=1; s<32; ++s){        // warmup (no store)
                VIT_STEP(word, s)
            }
        }
        const int s0i = (c==0) ? 1 : 0;
        for (int s=s0i; s<32; ++s){          // real: advance + emit backpointer
            VIT_STEP_H(word, WARM + s, tstart + s)
        }
        if (owner){
            float val = act ? (sc + et[j]) : -1e30f;
            int   tix = act ? j : 1000;
            #pragma unroll
            for (int off=32; off>=1; off>>=1){
                float ov = __shfl_xor(val, off, 64);
                int   oi = __shfl_xor(tix, off, 64);
                if (ov > val || (ov==val && oi<tix)){ val=ov; tix=oi; }
            }
            if (lane==0) ((int*)(ws+TAG_OFF))[b] = tix;
        }
    } else {
        const int* lb = labels + b*Tn;
        int last = -1;
        #pragma unroll
        for (int k=0;k<8;++k){ int mv = (lb[k*64+lane] != -100) ? 1 : 0; if (mv) last = k*64+lane; }
        #pragma unroll
        for (int off=32; off>=1; off>>=1){ int o = __shfl_xor(last, off, 64); last = (o>last)?o:last; }
        const bool owner = (last >= tstart) && (last < tstart+32);

        unsigned long long word = __ballot(lb[w0 + lane] != -100);

        float Ec[Ln];
        #pragma unroll
        for (int i=0;i<Ln;++i) Ec[i] = __expf(trans[i*Ln + j]);

        float p, M = 0.f, La;
        if (c==0){
            p = act ? __expf(st[j] + em_s[j]) : 0.f;
            float sm = p;
            #pragma unroll
            for (int off=32; off>=1; off>>=1) sm += __shfl_xor(sm, off, 64);
            La = __logf(sm);                 // M=0 at init
        } else {
            p = act ? 1.f : 0.f;
            La = 0.f;                        // set after warmup
        }

        const float* epr = &em_s[Ln + j];
        float e1 = epr[0]; epr += Ln;
        float e2 = epr[0]; epr += Ln;

        if (c > 0){
            for (int s=1; s<32; ++s){        // warmup
                NLL_STEP(word, s)
            }
            float sm = act ? p : 0.f;
            #pragma unroll
            for (int off=32; off>=1; off>>=1) sm += __shfl_xor(sm, off, 64);
            La = M + __logf(sm);
        }
        const int s0i = (c==0) ? 1 : 0;
        for (int s=s0i; s<32; ++s){          // real
            NLL_STEP(word, WARM + s)
        }
        float sm = act ? p : 0.f;
        #pragma unroll
        for (int off=32; off>=1; off>>=1) sm += __shfl_xor(sm, off, 64);
        float Lb = M + __logf(sm);
        if (lane==0) (ws+DELTA_OFF)[b*NCH + c] = Lb - La;
        if (c==0 && lane==0) (ws+LA0_OFF)[b] = La;
        if (owner){
            float wsum = act ? (p * __expf(et[j])) : 0.f;
            #pragma unroll
            for (int off=32; off>=1; off>>=1) wsum += __shfl_xor(wsum, off, 64);
            if (lane==0) (ws+W_OFF2)[b] = __logf(wsum) - __logf(sm);
        }
    }
}

// ---------------- post: blocks 0..63 backtrack+logits (hist precomputed); 64..127 gold score ----------------
__global__ __launch_bounds__(512) void post_kernel(
    const float* __restrict__ em, const int* __restrict__ labels,
    const int* __restrict__ amask, const float* __restrict__ st,
    const float* __restrict__ et, const float* __restrict__ trans,
    float* __restrict__ ws, float* __restrict__ logits)
{
    const int b    = blockIdx.x & (Bn-1);
    const int mode = blockIdx.x >> 6;
    const int tid  = threadIdx.x;

    if (mode == 0){
        __shared__ unsigned char hist_s[Tn*Ln];
        __shared__ int lab_s[Tn];
        __shared__ int path_s[Tn];
        __shared__ unsigned char comp_s[64*Ln];
        __shared__ unsigned char ent_s[64];
        lab_s[tid] = amask[b*Tn + tid];
        const unsigned char* hg = (const unsigned char*)(logits + (size_t)b*Tn*Ln);
        for (int i=tid; i<Tn*Ln; i+=512) hist_s[i] = hg[i];
        __syncthreads();
        if (tid < 64){
            unsigned char cur[Ln];
            #pragma unroll
            for (int q=0;q<Ln;++q) cur[q] = (unsigned char)q;
            #pragma unroll
            for (int k=8;k>=1;--k){
                int ta = 8*tid + k;
                if (ta < Tn){
                    const unsigned char* hr = &hist_s[ta*Ln];
                    #pragma unroll
                    for (int q=0;q<Ln;++q) cur[q] = hr[cur[q]];
                }
            }
            #pragma unroll
            for (int q=0;q<Ln;++q) comp_s[tid*Ln+q] = cur[q];
        }
        __syncthreads();
        if (tid==0){
            int cg = ((const int*)(ws+TAG_OFF))[b];
            for (int l=63;l>=0;--l){ ent_s[l]=(unsigned char)cg; cg = comp_s[l*Ln+cg]; }
        }
        __syncthreads();
        if (tid < 64){
            int s = ent_s[tid];
            if (tid==63) path_s[Tn-1] = s;
            #pragma unroll
            for (int k=8;k>=1;--k){
                int ta = 8*tid + k;
                if (ta < Tn){ s = hist_s[ta*Ln+s]; path_s[ta-1] = s; }
            }
        }
        __syncthreads();   // all hist reads done; overwrite region with one-hot
        float* lg = logits + (size_t)b*Tn*Ln;
        for (int id2=tid; id2<Tn*Ln; id2+=512){
            int t = id2/Ln; int jj = id2 - t*Ln;
            lg[id2] = (lab_s[t] && path_s[t]==jj) ? 1.0f : 0.0f;
        }
    } else {
        __shared__ float red_s[8];
        __shared__ int  redc_s[8];
        const int* lb = labels + b*Tn;
        int labt = lb[tid];
        float term = 0.f;
        int c = (tid==0 || labt != -100) ? 1 : 0;
        if (tid>=1 && labt != -100){
            int lp = lb[tid-1]; if (lp<0) lp=0;
            term = trans[lp*Ln+labt] + em[((size_t)b*Tn+tid)*Ln + labt];
        }
        #pragma unroll
        for (int off=32; off>=1; off>>=1){
            term += __shfl_xor(term, off, 64);
            c    += __shfl_xor(c,    off, 64);
        }
        int w = tid>>6;
        if ((tid&63)==0){ red_s[w]=term; redc_s[w]=c; }
        __syncthreads();
        if (tid==0){
            float sum=0.f; int cnt=0;
            #pragma unroll
            for (int q=0;q<8;++q){ sum+=red_s[q]; cnt+=redc_s[q]; }
            int l0 = lb[0]; int tag0 = l0<0?0:l0;
            float score = st[tag0] + em[(size_t)b*Tn*Ln + tag0] + sum;
            int li = cnt-1; int ll = lb[li]; int lt = ll<0?0:ll;
            score += et[lt];
            (ws+SCORE_OFF)[b] = score;
        }
    }
}

// ---------------- finalize: nll = -mean(score - logZ) ----------------
__global__ __launch_bounds__(64) void fin_kernel(const float* __restrict__ ws,
                                                 float* __restrict__ out0)
{
    const int b = threadIdx.x;
    float logZ = (ws+LA0_OFF)[b] + (ws+W_OFF2)[b];
    #pragma unroll
    for (int c=0;c<NCH;++c) logZ += (ws+DELTA_OFF)[b*NCH + c];
    float v = (ws+SCORE_OFF)[b] - logZ;
    #pragma unroll
    for (int off=32; off>=1; off>>=1) v += __shfl_xor(v, off, 64);
    if (b==0) out0[0] = -(v * (1.0f/64.0f));
}

extern "C" void kernel_launch(void* const* d_in, const int* in_sizes, int n_in,
                              void* d_out, int out_size, void* d_ws, size_t ws_size,
                              hipStream_t stream)
{
    (void)in_sizes; (void)n_in; (void)out_size; (void)ws_size;
    const float* hidden = (const float*)d_in[0];
    const float* W      = (const float*)d_in[1];
    const float* bias   = (const float*)d_in[2];
    const float* st     = (const float*)d_in[3];
    const float* et     = (const float*)d_in[4];
    const float* trans  = (const float*)d_in[5];
    const int*   labels = (const int*)d_in[6];
    const int*   amask  = (const int*)d_in[7];

    float* out    = (float*)d_out;
    float* nll    = out;
    float* logits = out + 1;
    float* em     = out + 1 + EM_ELEMS;
    float* ws     = (float*)d_ws;

    emis_kernel<<<dim3(Bn*Tn/64), dim3(256), 0, stream>>>(hidden, W, bias, em);
    chunk_scan<<<dim3(2048), dim3(64), 0, stream>>>(em, labels, amask, st, et, trans, ws, logits);
    post_kernel<<<dim3(2*Bn), dim3(512), 0, stream>>>(em, labels, amask, st, et, trans, ws, logits);
    fin_kernel<<<dim3(1), dim3(64), 0, stream>>>(ws, nll);
}